// Round 4
// baseline (2477.426 us; speedup 1.0000x reference)
//
#include <hip/hip_runtime.h>
#include <stdint.h>
#include <stddef.h>

#define TSEQ 512
#define NB   64
#define DI   1024
#define DHID 1024
#define NG   4096
#define NGRP 8     // batch groups (8 rows each), one per XCD (runtime-verified)
#define WPG  32    // workgroups per group (32 hidden units each)
#define NWGS 256   // persistent workgroups (1 per CU)
#define FPAD 32    // flag padding: 32 uints = 128 B = one cache line per flag

typedef __attribute__((ext_vector_type(8))) short short8;
typedef __attribute__((ext_vector_type(4))) float f32x4;

__device__ __forceinline__ unsigned short f2bf(float f) {
  union { float f; uint32_t u; } v; v.f = f;
  uint32_t u = v.u;
  uint32_t r = u + 0x7fffu + ((u >> 16) & 1u);
  return (unsigned short)(r >> 16);
}
__device__ __forceinline__ float bf2f(unsigned short b) {
  union { uint32_t u; float f; } v; v.u = ((uint32_t)b) << 16;
  return v.f;
}
__device__ __forceinline__ float fsigm(float x) { return 1.0f / (1.0f + __expf(-x)); }
__device__ __forceinline__ float ftanh(float x) { return 1.0f - 2.0f / (__expf(2.0f * x) + 1.0f); }

__device__ __forceinline__ void gll16(const void* g, void* l) {
  __builtin_amdgcn_global_load_lds(
      (const __attribute__((address_space(1))) void*)g,
      (__attribute__((address_space(3))) void*)l, 16, 0, 0);
}

// ---- Scoped communication ops.
// LOCAL=true : sc0 only -> serviced at this XCD's L2 (~200cy). Data-safe ONLY
//              when producer+consumer share the L2 (verified by XCC vote).
// LOCAL=false: sc0 sc1 -> coherence point is the memory-side LLC (any placement).
template <bool LOCAL> __device__ __forceinline__ void st_u32(void* a, uint32_t v) {
  if (LOCAL) asm volatile("global_store_dword %0, %1, off sc0" :: "v"(a), "v"(v) : "memory");
  else       asm volatile("global_store_dword %0, %1, off sc0 sc1" :: "v"(a), "v"(v) : "memory");
}
template <bool LOCAL> __device__ __forceinline__ uint32_t ld_u32(const void* a) {
  uint32_t v;
  if (LOCAL) asm volatile("global_load_dword %0, %1, off sc0" : "=v"(v) : "v"(a) : "memory");
  else       asm volatile("global_load_dword %0, %1, off sc0 sc1" : "=v"(v) : "v"(a) : "memory");
  return v;
}
template <bool LOCAL> __device__ __forceinline__ short8 ld_b128(const void* a) {
  short8 v;
  if (LOCAL) asm volatile("global_load_dwordx4 %0, %1, off sc0" : "=v"(v) : "v"(a) : "memory");
  else       asm volatile("global_load_dwordx4 %0, %1, off sc0 sc1" : "=v"(v) : "v"(a) : "memory");
  return v;
}

// ---------------- K1: x fp32 -> bf16 ----------------
__global__ void k_convert_x(const float* __restrict__ x, unsigned short* __restrict__ xb, int n4) {
  int idx = blockIdx.x * blockDim.x + threadIdx.x;
  int stride = gridDim.x * blockDim.x;
  const float4* xf = (const float4*)x;
  for (int i = idx; i < n4; i += stride) {
    float4 v = xf[i];
    unsigned short o0 = f2bf(v.x), o1 = f2bf(v.y), o2 = f2bf(v.z), o3 = f2bf(v.w);
    uint2 packed;
    packed.x = (uint32_t)o0 | ((uint32_t)o1 << 16);
    packed.y = (uint32_t)o2 | ((uint32_t)o3 << 16);
    ((uint2*)xb)[i] = packed;
  }
}

// ---------------- K2: transpose W [1024][4096] fp32 -> [4096][1024] bf16 ----------------
__global__ void k_transpose_w(const float* __restrict__ w, unsigned short* __restrict__ wt) {
  __shared__ float tile[32][33];
  int n0 = blockIdx.x * 32;
  int k0 = blockIdx.y * 32;
  int c = threadIdx.x & 31, r0 = threadIdx.x >> 5;
  for (int r = r0; r < 32; r += 8)
    tile[r][c] = w[(size_t)(k0 + r) * NG + n0 + c];
  __syncthreads();
  for (int r = r0; r < 32; r += 8)
    wt[(size_t)(n0 + r) * 1024 + k0 + c] = f2bf(tile[c][r]);
}

// ---------------- K3: init (h0->bf16 blocked buf0, bsum, flag+vote slots) ----------------
// h ping-pong layout: [g(8)][w(32)][b(8)][u(32)] -- producer WG owns contiguous 512B.
__global__ void k_init(const float* __restrict__ h0, const float* __restrict__ b_ih,
                       const float* __restrict__ b_hh, unsigned short* __restrict__ hbuf0,
                       float* __restrict__ bsum, unsigned* __restrict__ arrive) {
  int i = blockIdx.x * 256 + threadIdx.x;
  if (i < NB * DHID) {
    int bg = i >> 10, un = i & 1023;
    int gg = bg >> 3, bb = bg & 7, ww = un >> 5, uu = un & 31;
    hbuf0[(((size_t)gg * WPG + ww) * 8 + bb) * 32 + uu] = f2bf(h0[i]);
  }
  if (i < NG) bsum[i] = b_ih[i] + b_hh[i];
  if (i < NGRP * WPG * FPAD * 2) arrive[i] = 0u;  // [0]: step flags, [1]: votes
}

// ---------------- K4: pregate GEMM  pg = x_bf16 @ W_ih (permuted layout) ----------------
// Output permuted for k_lstm: idx = ((t*8+g)*32+w)*1024 + gate*256 + b*32 + u
template <bool PF32>
__global__ __launch_bounds__(256, 2) void k_gemm_pregates(
    const unsigned short* __restrict__ xb,
    const unsigned short* __restrict__ wt,
    void* __restrict__ pg) {
  __shared__ char lds_raw[32768];
  char* As = lds_raw;
  char* Bs = lds_raw + 16384;

  const int wave = threadIdx.x >> 6;
  const int lane = threadIdx.x & 63;
  const int ln = lane & 15, quad = lane >> 4;
  const int m0 = blockIdx.x * 128;
  const int n0 = blockIdx.y * 128;
  const int mw = (wave >> 1) * 64, nw = (wave & 1) * 64;

  f32x4 acc[4][4] = {};

  for (int kc = 0; kc < 16; ++kc) {
    __syncthreads();
#pragma unroll
    for (int i = 0; i < 4; ++i) {
      int s = wave * 256 + i * 64 + lane;
      int row = s >> 3;
      int kg = (s & 7) ^ (row & 7);
      gll16(xb + (size_t)(m0 + row) * 1024 + kc * 64 + kg * 8, As + s * 16);
      gll16(wt + (size_t)(n0 + row) * 1024 + kc * 64 + kg * 8, Bs + s * 16);
    }
    __syncthreads();

    short8 a[2][4], b[2][4];
#pragma unroll
    for (int kt = 0; kt < 2; ++kt) {
      int kg = kt * 4 + quad;
#pragma unroll
      for (int mt = 0; mt < 4; ++mt) {
        int row = mw + mt * 16 + ln;
        a[kt][mt] = *(const short8*)(As + (row * 8 + (kg ^ (row & 7))) * 16);
      }
#pragma unroll
      for (int nt = 0; nt < 4; ++nt) {
        int row = nw + nt * 16 + ln;
        b[kt][nt] = *(const short8*)(Bs + (row * 8 + (kg ^ (row & 7))) * 16);
      }
    }
#pragma unroll
    for (int kt = 0; kt < 2; ++kt)
#pragma unroll
      for (int mt = 0; mt < 4; ++mt)
#pragma unroll
        for (int nt = 0; nt < 4; ++nt)
          acc[mt][nt] = __builtin_amdgcn_mfma_f32_16x16x32_bf16(a[kt][mt], b[kt][nt], acc[mt][nt], 0, 0, 0);
  }

#pragma unroll
  for (int mt = 0; mt < 4; ++mt)
#pragma unroll
    for (int nt = 0; nt < 4; ++nt)
#pragma unroll
      for (int r = 0; r < 4; ++r) {
        int rowg = m0 + mw + mt * 16 + quad * 4 + r;
        int colg = n0 + nw + nt * 16 + ln;
        int t = rowg >> 6, bglob = rowg & 63;
        int gb = bglob >> 3, bl = bglob & 7;
        int gate = colg >> 10, j = colg & 1023;
        int w = j >> 5, uu = j & 31;
        size_t idx = (((size_t)t * NGRP + gb) * WPG + w) * 1024 + (size_t)gate * 256 + bl * 32 + uu;
        if (PF32)
          ((float*)pg)[idx] = acc[mt][nt][r];
        else
          ((unsigned short*)pg)[idx] = f2bf(acc[mt][nt][r]);
      }
}

// ---------------- K5: persistent recurrent kernel ----------------
// 8 groups x 8 batch rows x 32 WGs x 32 hidden units. Group = bid&7 so under the
// round-robin dispatch each group sits on ONE XCD; verified at runtime by
// HW_REG_XCC_ID vote (unanimous -> sc0/L2 data path; else -> sc0sc1/LLC fallback,
// correct for any placement). W_hh slice (256 KB/WG) lives ENTIRELY in VGPRs
// (wreg[8][8] = 256 regs/lane, statically indexed). M=16 MFMA with 8 valid batch
// rows (rows 8-15 duplicated, discarded). K split across 4 waves; partials via gl2.
// HANG-HARDENED vs R3: flag stores are ALWAYS system-scope (sc0 sc1) and the
// LOCAL poll issues an authoritative sc0sc1 read every 8th iteration, so progress
// is guaranteed under any sc-bit semantics; only bulk h data rides the L2 path
// (same physical L2 when vote passes -> staleness impossible).
template <bool LOCAL, bool PF32>
__device__ __forceinline__ void lstm_loop(
    const unsigned short* __restrict__ whhT, const void* __restrict__ pg,
    const float* __restrict__ c0, const float* __restrict__ bsum,
    unsigned short* __restrict__ hbuf, float* __restrict__ out,
    unsigned* __restrict__ flags, float (*gl2)[8][8][17], int g, int w) {
  const int tid = threadIdx.x;
  const int wave = tid >> 6, lane = tid & 63;
  const int ln = lane & 15, quad = lane >> 4;

  // ---- W_hh slice -> registers (B-frag layout: col=ln, k=quad*8+j within kt) ----
  // wreg[cb][kt]: cb = gate*2 + colhalf; this wave covers K rows [wave*256, +256).
  short8 wreg[8][8];
#pragma unroll
  for (int cb = 0; cb < 8; ++cb) {
    const unsigned short* wcol = whhT +
        (size_t)((cb >> 1) * 1024 + w * 32 + (cb & 1) * 16 + ln) * 1024 +
        wave * 256 + quad * 8;
#pragma unroll
    for (int kt = 0; kt < 8; ++kt)
      wreg[cb][kt] = *(const short8*)(wcol + kt * 32);
  }
#pragma unroll
  for (int cb = 0; cb < 8; ++cb)
#pragma unroll
    for (int kt = 0; kt < 8; ++kt)
      asm volatile("" : "+v"(wreg[cb][kt]));  // pin in VGPRs, forbid remat

  const int b = tid >> 5, u = tid & 31;
  const int bg = g * 8 + b;
  const int un = w * 32 + u;
  float cst = c0[(size_t)bg * DHID + un];
  const float bs0 = bsum[un], bs1 = bsum[1024 + un],
              bs2 = bsum[2048 + un], bs3 = bsum[3072 + un];

  const size_t out_hlast = (size_t)TSEQ * NB * DHID;
  const size_t out_clast = out_hlast + (size_t)NB * DHID;

  float p0, p1, p2, p3;
#define LDPG(T)                                                                      \
  {                                                                                  \
    size_t base = (((size_t)(T) * NGRP + g) * WPG + w) * 1024 + (size_t)b * 32 + u;  \
    if (PF32) {                                                                      \
      const float* pp = (const float*)pg;                                            \
      p0 = pp[base]; p1 = pp[base + 256]; p2 = pp[base + 512]; p3 = pp[base + 768];  \
    } else {                                                                         \
      const unsigned short* pp = (const unsigned short*)pg;                          \
      p0 = bf2f(pp[base]); p1 = bf2f(pp[base + 256]);                                \
      p2 = bf2f(pp[base + 512]); p3 = bf2f(pp[base + 768]);                          \
    }                                                                                \
  }
  LDPG(0);

  const int hoff_a = (ln & 7) * 32 + quad * 8;  // A-frag per-lane elem offset

  for (int t = 0; t < TSEQ; ++t) {
    const unsigned short* hg = hbuf + (size_t)(t & 1) * (NB * DHID) + (size_t)g * (WPG * 256);
    unsigned short* hog = hbuf + (size_t)((t + 1) & 1) * (NB * DHID) +
                          (size_t)g * (WPG * 256) + w * 256;

    // ---- A-frags: wave's K-quarter, scoped loads ----
    short8 afr[8];
#pragma unroll
    for (int j = 0; j < 8; ++j)
      afr[j] = ld_b128<LOCAL>(hg + (wave * 8 + j) * 256 + hoff_a);
    asm volatile("s_waitcnt vmcnt(0)" ::: "memory");
    __builtin_amdgcn_sched_barrier(0);

    // ---- all 4 gates (8 col-blocks) over this wave's K-quarter, B from VGPRs ----
    f32x4 acc[8] = {};
#pragma unroll
    for (int j = 0; j < 8; ++j)
#pragma unroll
      for (int cb = 0; cb < 8; ++cb)
        acc[cb] = __builtin_amdgcn_mfma_f32_16x16x32_bf16(afr[j], wreg[cb][j], acc[cb], 0, 0, 0);

    if (quad < 2) {  // only rows 0-7 are real
#pragma unroll
      for (int cb = 0; cb < 8; ++cb)
#pragma unroll
        for (int r = 0; r < 4; ++r)
          gl2[wave][cb][quad * 4 + r][ln] = acc[cb][r];
    }
    __syncthreads();

    // ---- activation (1 element/thread), reduce 4 K-partials ----
    const int cbl = u >> 4, lnl = u & 15;
    float gi = ((gl2[0][0 + cbl][b][lnl] + gl2[1][0 + cbl][b][lnl]) +
                (gl2[2][0 + cbl][b][lnl] + gl2[3][0 + cbl][b][lnl])) + p0 + bs0;
    float gf = ((gl2[0][2 + cbl][b][lnl] + gl2[1][2 + cbl][b][lnl]) +
                (gl2[2][2 + cbl][b][lnl] + gl2[3][2 + cbl][b][lnl])) + p1 + bs1;
    float gg = ((gl2[0][4 + cbl][b][lnl] + gl2[1][4 + cbl][b][lnl]) +
                (gl2[2][4 + cbl][b][lnl] + gl2[3][4 + cbl][b][lnl])) + p2 + bs2;
    float go = ((gl2[0][6 + cbl][b][lnl] + gl2[1][6 + cbl][b][lnl]) +
                (gl2[2][6 + cbl][b][lnl] + gl2[3][6 + cbl][b][lnl])) + p3 + bs3;
    float i_ = fsigm(gi), f_ = fsigm(gf), g_ = ftanh(gg), o_ = fsigm(go);
    float cn = f_ * cst + i_ * g_;
    cst = cn;
    float h = o_ * ftanh(cn);
    out[((size_t)t * NB + bg) * DHID + un] = h;

    // h store: pack 2 bf16/dword, scoped (L2-local or LLC)
    float hn = __shfl_xor(h, 1);
    if (!(u & 1)) {
      uint32_t pk = (uint32_t)f2bf(h) | ((uint32_t)f2bf(hn) << 16);
      st_u32<LOCAL>((void*)(hog + b * 32 + u), pk);
    }

    if (t == TSEQ - 1) {
      out[out_hlast + (size_t)bg * DHID + un] = h;
      out[out_clast + (size_t)bg * DHID + un] = cn;
    }

    // ---- group barrier: ballot, one cache line per flag ----
    if (t < TSEQ - 1) {
      asm volatile("s_waitcnt vmcnt(0)" ::: "memory");  // h stores at coherence point
      __syncthreads();
      // flag store ALWAYS system-scope: visible to LLC pollers AND same-L2 pollers
      if (tid == 0) st_u32<false>((void*)(flags + w * FPAD), (uint32_t)(t + 1));
      LDPG(t + 1);  // prefetch next pg; overlaps the spin
      if (tid < 64) {
        const unsigned tgt = (unsigned)(t + 1);
        int it = 0;
        while (true) {
          unsigned v;
          if (LOCAL && ((++it) & 7))
            v = ld_u32<true>((const void*)(flags + (tid & 31) * FPAD));
          else
            v = ld_u32<false>((const void*)(flags + (tid & 31) * FPAD));
          asm volatile("s_waitcnt vmcnt(0)" ::: "memory");
          if (__all((int)(v >= tgt))) break;
          __builtin_amdgcn_s_sleep(1);
        }
      }
      __syncthreads();
    }
  }
#undef LDPG
}

template <bool PF32>
__global__ __launch_bounds__(256, 1) void k_lstm(
    const unsigned short* __restrict__ whhT,  // [4096][1024] bf16
    const void* __restrict__ pg,
    const float* __restrict__ c0,
    const float* __restrict__ bsum,
    unsigned short* __restrict__ hbuf,  // [2][NGRP][WPG][8][32] bf16
    float* __restrict__ out,            // [512][64][1024] ++ h_last ++ c_last
    unsigned* __restrict__ arrive) {    // [2][NGRP][WPG][FPAD]: flags, votes
  const int bid = blockIdx.x;
  const int g = bid & 7;   // batch group == expected XCD under round-robin
  const int w = bid >> 3;  // wg within group
  const int tid = threadIdx.x;

  __shared__ float gl2s[4][8][8][17];
  __shared__ int smode;

  unsigned* flags = arrive + (size_t)g * WPG * FPAD;
  unsigned* votes = arrive + (size_t)NGRP * WPG * FPAD + (size_t)g * WPG * FPAD;

  // ---- one-time placement vote (always system-scope; converges because all
  // 256 WGs are co-resident at 1 WG/CU) ----
  int xcc;
  asm volatile("s_getreg_b32 %0, hwreg(HW_REG_XCC_ID)" : "=s"(xcc));
  unsigned myvote = (xcc == g) ? 1u : 2u;
  if (tid == 0) st_u32<false>((void*)(votes + w * FPAD), myvote);
  if (tid < 64) {
    int loc = 0;
    while (true) {
      unsigned v = ld_u32<false>((const void*)(votes + (tid & 31) * FPAD));
      asm volatile("s_waitcnt vmcnt(0)" ::: "memory");
      if (__all((int)(v != 0u))) { loc = __all((int)(v == 1u)); break; }
      __builtin_amdgcn_s_sleep(2);
    }
    if (tid == 0) smode = loc;
  }
  __syncthreads();
  const int local = smode;

  if (local)
    lstm_loop<true, PF32>(whhT, pg, c0, bsum, hbuf, out, flags, gl2s, g, w);
  else
    lstm_loop<false, PF32>(whhT, pg, c0, bsum, hbuf, out, flags, gl2s, g, w);
}

// ---------------- launcher ----------------
static inline size_t align_up(size_t x, size_t a) { return (x + a - 1) & ~(a - 1); }

extern "C" void kernel_launch(void* const* d_in, const int* in_sizes, int n_in,
                              void* d_out, int out_size, void* d_ws, size_t ws_size,
                              hipStream_t stream) {
  const float* x    = (const float*)d_in[0];
  const float* c0   = (const float*)d_in[1];
  const float* h0   = (const float*)d_in[2];
  const float* W_ih = (const float*)d_in[3];
  const float* W_hh = (const float*)d_in[4];
  const float* b_ih = (const float*)d_in[5];
  const float* b_hh = (const float*)d_in[6];
  float* out = (float*)d_out;

  const size_t pg_elems = (size_t)TSEQ * NB * NG;
  const size_t xb_bytes = (size_t)TSEQ * NB * DI * 2;
  const size_t wt_bytes = (size_t)NG * 1024 * 2;
  const size_t hb_bytes = (size_t)2 * NB * DHID * 2;
  const size_t bsum_bytes = (size_t)NG * 4;
  const size_t arr_bytes = (size_t)NGRP * WPG * FPAD * 4 * 2;

  auto layout = [&](size_t pg_bytes, size_t* offs) {
    size_t o = 0;
    offs[0] = o; o = align_up(o + pg_bytes, 256);
    offs[1] = o; o = align_up(o + xb_bytes, 256);
    offs[2] = o; o = align_up(o + wt_bytes, 256);
    offs[3] = o; o = align_up(o + wt_bytes, 256);
    offs[4] = o; o = align_up(o + hb_bytes, 256);
    offs[5] = o; o = align_up(o + bsum_bytes, 256);
    offs[6] = o; o = align_up(o + arr_bytes, 256);
    return o;
  };
  size_t offs[7];
  size_t need_f32 = layout(pg_elems * 4, offs);
  bool pf32 = ws_size >= need_f32;
  if (!pf32) layout(pg_elems * 2, offs);

  char* ws = (char*)d_ws;
  void* pg = ws + offs[0];
  unsigned short* xb   = (unsigned short*)(ws + offs[1]);
  unsigned short* wihT = (unsigned short*)(ws + offs[2]);
  unsigned short* whhT = (unsigned short*)(ws + offs[3]);
  unsigned short* hbuf = (unsigned short*)(ws + offs[4]);
  float* bsum = (float*)(ws + offs[5]);
  unsigned* arrive = (unsigned*)(ws + offs[6]);

  k_convert_x<<<2048, 256, 0, stream>>>(x, xb, (int)((size_t)TSEQ * NB * DI / 4));
  k_transpose_w<<<dim3(NG / 32, 1024 / 32), 256, 0, stream>>>(W_ih, wihT);
  k_transpose_w<<<dim3(NG / 32, 1024 / 32), 256, 0, stream>>>(W_hh, whhT);
  k_init<<<(NB * DHID + 255) / 256, 256, 0, stream>>>(h0, b_ih, b_hh, hbuf, bsum, arrive);

  dim3 ggrid(TSEQ * NB / 128, NG / 128);
  if (pf32)
    k_gemm_pregates<true><<<ggrid, 256, 0, stream>>>(xb, wihT, pg);
  else
    k_gemm_pregates<false><<<ggrid, 256, 0, stream>>>(xb, wihT, pg);

  if (pf32)
    k_lstm<true><<<NWGS, 256, 0, stream>>>(whhT, pg, c0, bsum, hbuf, out, arrive);
  else
    k_lstm<false><<<NWGS, 256, 0, stream>>>(whhT, pg, c0, bsum, hbuf, out, arrive);
}